// Round 8
// baseline (86.873 us; speedup 1.0000x reference)
//
#include <hip/hip_runtime.h>
#include <math.h>

// Problem constants (from reference)
#define Bb 4
#define Ss 256
#define Hh 768
#define Ee 200
#define Rr 200
#define Dd 25
#define NET 9                  // NUM_ENT_TYPES
#define NRT 5                  // NUM_REL_TYPES
#define ENT_REPR (Dd + 2*Hh)   // 1561
#define REL_REPR (2*Dd + 3*Hh) // 2354
#define TPB 384                // waves 0-2: entity item, waves 3-5: relation item
#define H4 (Hh/4)              // 192 float4 per lhs row

// Self-contained single kernel (no d_ws — round 6 showed the ws handoff
// diverges under graph replay). One block = one entity item (threads 0..191)
// + one relation item (threads 192..383), as independent thread-groups
// sharing only 2 barriers. This halves the number of block-lifetimes
// (1600 -> 800) at unchanged resident-wave count, attacking the measured
// ~10us-per-block latency chain (round-3 profile: occ 2.4 waves/CU over
// 74us with 4800 waves).
//
// Masks are contiguous spans (len in [1,29], start in [0,226)). Masked
// maxpool == max over [first,last] clamped with 0.

__device__ __forceinline__ float4 max4(float4 a, float4 b) {
    return make_float4(fmaxf(a.x, b.x), fmaxf(a.y, b.y),
                       fmaxf(a.z, b.z), fmaxf(a.w, b.w));
}

__device__ __forceinline__ void span_decode(const unsigned long long* bal,
                                            int& first, int& last, int& length)
{
    const unsigned long long b0 = bal[0], b1 = bal[1], b2 = bal[2], b3 = bal[3];
    length = __popcll(b0) + __popcll(b1) + __popcll(b2) + __popcll(b3);
    if (b0)      first = __ffsll(b0) - 1;
    else if (b1) first = 63  + __ffsll(b1);
    else if (b2) first = 127 + __ffsll(b2);
    else         first = 191 + __ffsll(b3);
    if (b3)      last = 255 - __clzll(b3);
    else if (b2) last = 191 - __clzll(b2);
    else if (b1) last = 127 - __clzll(b1);
    else         last = 63  - __clzll(b0);
}

// Batch-4 masked maxpool over this thread's float4 column. Tail rows clamp
// the ADDRESS to `last` (idempotent under max) — no OOB, no predicates.
__device__ __forceinline__ float4 pool4b(const float4* __restrict__ lb4,
                                         int col, int first, int last)
{
    float4 acc = make_float4(0.f, 0.f, 0.f, 0.f);  // 0-clamp built in
    for (int s = first; s <= last; s += 4) {
        const int r1 = min(s + 1, last);
        const int r2 = min(s + 2, last);
        const int r3 = min(s + 3, last);
        const float4 v0 = lb4[(size_t)s  * H4 + col];
        const float4 v1 = lb4[(size_t)r1 * H4 + col];
        const float4 v2 = lb4[(size_t)r2 * H4 + col];
        const float4 v3 = lb4[(size_t)r3 * H4 + col];
        acc = max4(acc, max4(max4(v0, v1), max4(v2, v3)));
    }
    return acc;
}

__global__ __launch_bounds__(TPB) void spert_fused(
    const float4* __restrict__ lhs4,     // B,S,H4
    const int*   __restrict__ ent_mask,  // B,E,S
    const int*   __restrict__ relations, // B,R,2
    const int*   __restrict__ rel_mask,  // B,R,S
    const float* __restrict__ size_emb,  // 100,D
    const float* __restrict__ span_w,    // NET,ENT_REPR
    const float* __restrict__ span_b,    // NET
    const float* __restrict__ rel_w,     // NRT,REL_REPR
    const float* __restrict__ rel_b,     // NRT
    float* __restrict__ ent_logit,       // B,E,NET
    float* __restrict__ rel_logit)       // B,R,NRT
{
    const int tid  = threadIdx.x;        // 0..383
    const int item = blockIdx.x;         // 0..799 (entity item == relation item idx)
    const int b    = item / Ee;          // Ee == Rr
    const int j    = item % Ee;          // entity e == relation r
    const float4* lb4 = lhs4 + (size_t)b * Ss * H4;

    __shared__ unsigned long long s_bal_e[4];
    __shared__ unsigned long long s_bal_r[3][4];
    __shared__ float s_part_e[3][NET];
    __shared__ float s_part_r[3][NRT];

    if (tid < 192) {
        // ================= entity group (waves 0-2) =================
        const int wave = tid >> 6;
        const int lane = tid & 63;

        const int* mrow = ent_mask + (size_t)(b*Ee + j)*Ss;
        {
            const unsigned long long bal = __ballot(mrow[tid] != 0);
            if (lane == 0) s_bal_e[wave] = bal;
        }
        if (tid < 64) {
            const unsigned long long bal = __ballot(mrow[192 + tid] != 0);
            if (tid == 0) s_bal_e[3] = bal;
        }
        __syncthreads();

        int first, last, length;
        span_decode(s_bal_e, first, last, length);

        const float4 v  = pool4b(lb4, tid, first, last);   // entity
        const float4 cx = lb4[tid];                        // ctx = lhs[b,0,:]
        const float  sz = (tid < Dd) ? size_emb[length * Dd + tid] : 0.0f;

        float sums[NET];
        #pragma unroll
        for (int t = 0; t < NET; ++t) {
            const float* w  = span_w + (size_t)t * ENT_REPR;
            const float* wa = w + 4*tid;
            const float* wb = w + Hh + 4*tid;
            float s = v.x*wa[0]  + v.y*wa[1]  + v.z*wa[2]  + v.w*wa[3]
                    + cx.x*wb[0] + cx.y*wb[1] + cx.z*wb[2] + cx.w*wb[3];
            if (tid < Dd) s += sz * w[2*Hh + tid];
            sums[t] = s;
        }
        #pragma unroll
        for (int t = 0; t < NET; ++t) {
            float s = sums[t];
            #pragma unroll
            for (int o = 32; o > 0; o >>= 1) s += __shfl_xor(s, o, 64);
            if (lane == 0) s_part_e[wave][t] = s;
        }
        __syncthreads();
        if (tid < NET) {
            ent_logit[(size_t)(b*Ee + j)*NET + tid] =
                s_part_e[0][tid] + s_part_e[1][tid] + s_part_e[2][tid] + span_b[tid];
        }
    } else {
        // ================= relation group (waves 3-5) =================
        const int t2   = tid - 192;      // 0..191
        const int wave = t2 >> 6;
        const int lane = t2 & 63;

        const int e1 = relations[(size_t)(b*Rr + j)*2 + 0];
        const int e2 = relations[(size_t)(b*Rr + j)*2 + 1];

        const int* mrc = rel_mask + (size_t)(b*Rr + j)*Ss;
        const int* mr1 = ent_mask + (size_t)(b*Ee + e1)*Ss;
        const int* mr2 = ent_mask + (size_t)(b*Ee + e2)*Ss;
        {
            const unsigned long long bc = __ballot(mrc[t2] != 0);
            const unsigned long long b1 = __ballot(mr1[t2] != 0);
            const unsigned long long b2 = __ballot(mr2[t2] != 0);
            if (lane == 0) {
                s_bal_r[0][wave] = bc;
                s_bal_r[1][wave] = b1;
                s_bal_r[2][wave] = b2;
            }
        }
        if (t2 < 64) {  // exactly wave 3 — full-wave ballots
            const unsigned long long bc = __ballot(mrc[192 + t2] != 0);
            const unsigned long long b1 = __ballot(mr1[192 + t2] != 0);
            const unsigned long long b2 = __ballot(mr2[192 + t2] != 0);
            if (t2 == 0) {
                s_bal_r[0][3] = bc;
                s_bal_r[1][3] = b1;
                s_bal_r[2][3] = b2;
            }
        }
        __syncthreads();

        int fc, lc, nc; span_decode(s_bal_r[0], fc, lc, nc);
        int f1, l1, n1; span_decode(s_bal_r[1], f1, l1, n1);
        int f2, l2, n2; span_decode(s_bal_r[2], f2, l2, n2);

        const float4 cx = pool4b(lb4, t2, fc, lc);   // rel_ctx
        const float4 a  = pool4b(lb4, t2, f1, l1);   // entity e1
        const float4 d  = pool4b(lb4, t2, f2, l2);   // entity e2
        const float sz1 = (t2 < Dd) ? size_emb[n1 * Dd + t2] : 0.0f;
        const float sz2 = (t2 < Dd) ? size_emb[n2 * Dd + t2] : 0.0f;

        float sums[NRT];
        #pragma unroll
        for (int t = 0; t < NRT; ++t) {
            const float* w  = rel_w + (size_t)t * REL_REPR;
            const float* wc = w + 4*t2;
            const float* wa = w + Hh + 4*t2;
            const float* wd = w + 2*Hh + 4*t2;
            float s = cx.x*wc[0] + cx.y*wc[1] + cx.z*wc[2] + cx.w*wc[3]
                    + a.x*wa[0]  + a.y*wa[1]  + a.z*wa[2]  + a.w*wa[3]
                    + d.x*wd[0]  + d.y*wd[1]  + d.z*wd[2]  + d.w*wd[3];
            if (t2 < Dd) s += sz1 * w[3*Hh + t2] + sz2 * w[3*Hh + Dd + t2];
            sums[t] = s;
        }
        #pragma unroll
        for (int t = 0; t < NRT; ++t) {
            float s = sums[t];
            #pragma unroll
            for (int o = 32; o > 0; o >>= 1) s += __shfl_xor(s, o, 64);
            if (lane == 0) s_part_r[wave][t] = s;
        }
        __syncthreads();
        if (t2 < NRT) {
            rel_logit[(size_t)(b*Rr + j)*NRT + t2] =
                s_part_r[0][t2] + s_part_r[1][t2] + s_part_r[2][t2] + rel_b[t2];
        }
    }
}

extern "C" void kernel_launch(void* const* d_in, const int* in_sizes, int n_in,
                              void* d_out, int out_size, void* d_ws, size_t ws_size,
                              hipStream_t stream) {
    const float* lhs       = (const float*)d_in[0];  // B,S,H
    const int*   ent_mask  = (const int*)  d_in[1];  // B,E,S
    const int*   relations = (const int*)  d_in[2];  // B,R,2
    const int*   rel_mask  = (const int*)  d_in[3];  // B,R,S
    const float* size_emb  = (const float*)d_in[4];  // 100,25
    const float* span_w    = (const float*)d_in[5];  // 9,1561
    const float* span_b    = (const float*)d_in[6];  // 9
    const float* rel_w     = (const float*)d_in[7];  // 5,2354
    const float* rel_b     = (const float*)d_in[8];  // 5

    float* ent_logit = (float*)d_out;                     // B*E*NET = 7200
    float* rel_logit = (float*)d_out + (size_t)Bb*Ee*NET; // B*R*NRT = 4000

    spert_fused<<<Bb*Ee, TPB, 0, stream>>>(
        (const float4*)lhs, ent_mask, relations, rel_mask, size_emb,
        span_w, span_b, rel_w, rel_b, ent_logit, rel_logit);
}

// Round 9
// 86.796 us; speedup vs baseline: 1.0009x; 1.0009x over previous
//
#include <hip/hip_runtime.h>
#include <math.h>

// Problem constants (from reference)
#define Bb 4
#define Ss 256
#define Hh 768
#define Ee 200
#define Rr 200
#define Dd 25
#define NET 9                  // NUM_ENT_TYPES
#define NRT 5                  // NUM_REL_TYPES
#define ENT_REPR (Dd + 2*Hh)   // 1561
#define REL_REPR (2*Dd + 3*Hh) // 2354
#define TPB 192                // 3 waves; thread owns one float4 channel column
#define H4 (Hh/4)              // 192 float4 per lhs row

// Self-contained single kernel (no d_ws — round 6 showed ws handoff diverges
// under graph replay). Round-9 change: span decode is WAVE-LOCAL (each lane
// reads int4 of the mask row; 6-step shuffle butterfly) — removes the first
// __syncthreads + its vmcnt(0) drain + the LDS ballot round trip from the
// per-block serial chain. Entity/relation blocks interleaved even/odd to
// balance the dispatch tail.
//
// Masks are contiguous spans (len in [1,29], start in [0,226)). Masked
// maxpool == max over [first,last] clamped with 0.

__device__ __forceinline__ float4 max4(float4 a, float4 b) {
    return make_float4(fmaxf(a.x, b.x), fmaxf(a.y, b.y),
                       fmaxf(a.z, b.z), fmaxf(a.w, b.w));
}

// Wave-local span decode from one int4 (4 mask positions) per lane.
__device__ __forceinline__ void span_wave(int4 m, int lane,
                                          int& first, int& last, int& length)
{
    const int p = lane * 4;
    int cnt = (m.x != 0) + (m.y != 0) + (m.z != 0) + (m.w != 0);
    int fm = m.x ? p : (m.y ? p+1 : (m.z ? p+2 : (m.w ? p+3 : 1024)));
    int lm = m.w ? p+3 : (m.z ? p+2 : (m.y ? p+1 : (m.x ? p : -1)));
    #pragma unroll
    for (int o = 32; o > 0; o >>= 1) {
        cnt += __shfl_xor(cnt, o, 64);
        fm   = min(fm, __shfl_xor(fm, o, 64));
        lm   = max(lm, __shfl_xor(lm, o, 64));
    }
    first = fm; last = lm; length = cnt;
}

// Batch-4 masked maxpool over this thread's float4 column. Tail rows clamp
// the ADDRESS to `last` (idempotent under max) — no OOB, no predicates.
__device__ __forceinline__ float4 pool4b(const float4* __restrict__ lb4,
                                         int col, int first, int last)
{
    float4 acc = make_float4(0.f, 0.f, 0.f, 0.f);  // 0-clamp built in
    for (int s = first; s <= last; s += 4) {
        const int r1 = min(s + 1, last);
        const int r2 = min(s + 2, last);
        const int r3 = min(s + 3, last);
        const float4 v0 = lb4[(size_t)s  * H4 + col];
        const float4 v1 = lb4[(size_t)r1 * H4 + col];
        const float4 v2 = lb4[(size_t)r2 * H4 + col];
        const float4 v3 = lb4[(size_t)r3 * H4 + col];
        acc = max4(acc, max4(max4(v0, v1), max4(v2, v3)));
    }
    return acc;
}

__global__ __launch_bounds__(TPB) void spert_fused(
    const float4* __restrict__ lhs4,     // B,S,H4
    const int*   __restrict__ ent_mask,  // B,E,S
    const int*   __restrict__ relations, // B,R,2
    const int*   __restrict__ rel_mask,  // B,R,S
    const float* __restrict__ size_emb,  // 100,D
    const float* __restrict__ span_w,    // NET,ENT_REPR
    const float* __restrict__ span_b,    // NET
    const float* __restrict__ rel_w,     // NRT,REL_REPR
    const float* __restrict__ rel_b,     // NRT
    float* __restrict__ ent_logit,       // B,E,NET
    float* __restrict__ rel_logit)       // B,R,NRT
{
    const int tid  = threadIdx.x;
    const int wave = tid >> 6;
    const int lane = tid & 63;
    const int item = blockIdx.x >> 1;    // 0..799
    const int b    = item / Ee;          // Ee == Rr
    const int j    = item % Ee;
    const float4* lb4 = lhs4 + (size_t)b * Ss * H4;

    __shared__ float s_part[3][NET];     // NET >= NRT

    if ((blockIdx.x & 1) == 0) {
        // ---------------- entity block ----------------
        const float4 cx = lb4[tid];      // ctx = lhs[b,0,:] — independent, first

        const int4 m = ((const int4*)(ent_mask + (size_t)(b*Ee + j)*Ss))[lane];
        int first, last, length;
        span_wave(m, lane, first, last, length);

        const float4 v  = pool4b(lb4, tid, first, last);   // entity
        const float  sz = (tid < Dd) ? size_emb[length * Dd + tid] : 0.0f;

        float sums[NET];
        #pragma unroll
        for (int t = 0; t < NET; ++t) {
            const float* w  = span_w + (size_t)t * ENT_REPR;
            const float* wa = w + 4*tid;        // entity segment
            const float* wb = w + Hh + 4*tid;   // ctx segment
            float s = v.x*wa[0]  + v.y*wa[1]  + v.z*wa[2]  + v.w*wa[3]
                    + cx.x*wb[0] + cx.y*wb[1] + cx.z*wb[2] + cx.w*wb[3];
            if (tid < Dd) s += sz * w[2*Hh + tid];
            sums[t] = s;
        }
        #pragma unroll
        for (int t = 0; t < NET; ++t) {
            float s = sums[t];
            #pragma unroll
            for (int o = 32; o > 0; o >>= 1) s += __shfl_xor(s, o, 64);
            if (lane == 0) s_part[wave][t] = s;
        }
        __syncthreads();
        if (tid < NET) {
            ent_logit[(size_t)(b*Ee + j)*NET + tid] =
                s_part[0][tid] + s_part[1][tid] + s_part[2][tid] + span_b[tid];
        }
    } else {
        // ---------------- relation block ----------------
        const int2 ee = ((const int2*)relations)[(size_t)b*Rr + j];
        const int e1 = ee.x, e2 = ee.y;

        const int4 mc = ((const int4*)(rel_mask + (size_t)(b*Rr + j)*Ss))[lane];
        const int4 m1 = ((const int4*)(ent_mask + (size_t)(b*Ee + e1)*Ss))[lane];
        const int4 m2 = ((const int4*)(ent_mask + (size_t)(b*Ee + e2)*Ss))[lane];

        // joint 3-span butterfly (shared shuffle steps)
        int fc, lc, nc, f1, l1, n1, f2, l2, n2;
        {
            const int p = lane * 4;
            int c0 = (mc.x!=0)+(mc.y!=0)+(mc.z!=0)+(mc.w!=0);
            int c1 = (m1.x!=0)+(m1.y!=0)+(m1.z!=0)+(m1.w!=0);
            int c2 = (m2.x!=0)+(m2.y!=0)+(m2.z!=0)+(m2.w!=0);
            int F0 = mc.x?p:(mc.y?p+1:(mc.z?p+2:(mc.w?p+3:1024)));
            int F1 = m1.x?p:(m1.y?p+1:(m1.z?p+2:(m1.w?p+3:1024)));
            int F2 = m2.x?p:(m2.y?p+1:(m2.z?p+2:(m2.w?p+3:1024)));
            int L0 = mc.w?p+3:(mc.z?p+2:(mc.y?p+1:(mc.x?p:-1)));
            int L1 = m1.w?p+3:(m1.z?p+2:(m1.y?p+1:(m1.x?p:-1)));
            int L2 = m2.w?p+3:(m2.z?p+2:(m2.y?p+1:(m2.x?p:-1)));
            #pragma unroll
            for (int o = 32; o > 0; o >>= 1) {
                c0 += __shfl_xor(c0, o, 64);
                c1 += __shfl_xor(c1, o, 64);
                c2 += __shfl_xor(c2, o, 64);
                F0 = min(F0, __shfl_xor(F0, o, 64));
                F1 = min(F1, __shfl_xor(F1, o, 64));
                F2 = min(F2, __shfl_xor(F2, o, 64));
                L0 = max(L0, __shfl_xor(L0, o, 64));
                L1 = max(L1, __shfl_xor(L1, o, 64));
                L2 = max(L2, __shfl_xor(L2, o, 64));
            }
            fc = F0; lc = L0; nc = c0;
            f1 = F1; l1 = L1; n1 = c1;
            f2 = F2; l2 = L2; n2 = c2;
        }

        const float4 cx = pool4b(lb4, tid, fc, lc);   // rel_ctx
        const float4 a  = pool4b(lb4, tid, f1, l1);   // entity e1
        const float4 d  = pool4b(lb4, tid, f2, l2);   // entity e2
        const float sz1 = (tid < Dd) ? size_emb[n1 * Dd + tid] : 0.0f;
        const float sz2 = (tid < Dd) ? size_emb[n2 * Dd + tid] : 0.0f;

        float sums[NRT];
        #pragma unroll
        for (int t = 0; t < NRT; ++t) {
            const float* w  = rel_w + (size_t)t * REL_REPR;
            const float* wc = w + 4*tid;
            const float* wa = w + Hh + 4*tid;
            const float* wd = w + 2*Hh + 4*tid;
            float s = cx.x*wc[0] + cx.y*wc[1] + cx.z*wc[2] + cx.w*wc[3]
                    + a.x*wa[0]  + a.y*wa[1]  + a.z*wa[2]  + a.w*wa[3]
                    + d.x*wd[0]  + d.y*wd[1]  + d.z*wd[2]  + d.w*wd[3];
            if (tid < Dd) s += sz1 * w[3*Hh + tid] + sz2 * w[3*Hh + Dd + tid];
            sums[t] = s;
        }
        #pragma unroll
        for (int t = 0; t < NRT; ++t) {
            float s = sums[t];
            #pragma unroll
            for (int o = 32; o > 0; o >>= 1) s += __shfl_xor(s, o, 64);
            if (lane == 0) s_part[wave][t] = s;
        }
        __syncthreads();
        if (tid < NRT) {
            rel_logit[(size_t)(b*Rr + j)*NRT + tid] =
                s_part[0][tid] + s_part[1][tid] + s_part[2][tid] + rel_b[tid];
        }
    }
}

extern "C" void kernel_launch(void* const* d_in, const int* in_sizes, int n_in,
                              void* d_out, int out_size, void* d_ws, size_t ws_size,
                              hipStream_t stream) {
    const float* lhs       = (const float*)d_in[0];  // B,S,H
    const int*   ent_mask  = (const int*)  d_in[1];  // B,E,S
    const int*   relations = (const int*)  d_in[2];  // B,R,2
    const int*   rel_mask  = (const int*)  d_in[3];  // B,R,S
    const float* size_emb  = (const float*)d_in[4];  // 100,25
    const float* span_w    = (const float*)d_in[5];  // 9,1561
    const float* span_b    = (const float*)d_in[6];  // 9
    const float* rel_w     = (const float*)d_in[7];  // 5,2354
    const float* rel_b     = (const float*)d_in[8];  // 5

    float* ent_logit = (float*)d_out;                     // B*E*NET = 7200
    float* rel_logit = (float*)d_out + (size_t)Bb*Ee*NET; // B*R*NRT = 4000

    spert_fused<<<2 * Bb * Ee, TPB, 0, stream>>>(
        (const float4*)lhs, ent_mask, relations, rel_mask, size_emb,
        span_w, span_b, rel_w, rel_b, ent_logit, rel_logit);
}